// Round 12
// baseline (9161.796 us; speedup 1.0000x reference)
//
#include <hip/hip_runtime.h>
#include <math.h>

#define D 4096
#define NB 128
#define KC 32
#define NT (D / NB)      // 32 tiles per side
#define LDP 40           // padded LDS row stride in bf16 elems (80 B)

typedef __attribute__((ext_vector_type(8))) short short8;
typedef __attribute__((ext_vector_type(4))) float f32x4;
typedef __attribute__((ext_vector_type(4))) unsigned int uint4v;
typedef unsigned short ush;

__device__ __forceinline__ float softplusf(float x) {
  return fmaxf(x, 0.0f) + log1pf(expf(-fabsf(x)));
}

struct HL { unsigned int h, l; };

__device__ __forceinline__ HL split2(float x0, float x1) {
  unsigned int b0 = __float_as_uint(x0), b1 = __float_as_uint(x1);
  unsigned int h0 = b0 & 0xFFFF0000u, h1 = b1 & 0xFFFF0000u;
  float r0 = x0 - __uint_as_float(h0);
  float r1 = x1 - __uint_as_float(h1);
  HL out;
  out.h = h1 | (h0 >> 16);
  out.l = (__float_as_uint(r1) & 0xFFFF0000u) | (__float_as_uint(r0) >> 16);
  return out;
}

// ---- flag primitives: relaxed LOAD polling, release-RMW signal (proven R9-R11)
__device__ __forceinline__ void wait_ge(unsigned* p, unsigned tgt) {
  if (threadIdx.x == 0) {
    while (__hip_atomic_load(p, __ATOMIC_RELAXED, __HIP_MEMORY_SCOPE_AGENT) < tgt)
      __builtin_amdgcn_s_sleep(16);
    __threadfence();
  }
  __syncthreads();
}

__device__ __forceinline__ void signal_add(unsigned* p) {
  __syncthreads();
  if (threadIdx.x == 0) {
    __threadfence();
    __hip_atomic_fetch_add(p, 1u, __ATOMIC_RELEASE, __HIP_MEMORY_SCOPE_AGENT);
  }
}

// ---------------- in-LDS potrf of a 128x128 tile (rcp chain) -----------------
__device__ void potrf_factor(float (*Ls)[NB + 1]) {
  int tid = threadIdx.x;
  int lane = tid & 63, wid = tid >> 6;
  int tx = tid & 15, ty = tid >> 4;

  for (int pp = 0; pp < 8; ++pp) {
    int pc0 = pp * 16;
    if (wid == 0) {
      int ra = lane, rb = lane + 64;
      bool va = (ra >= pc0), vb = (rb >= pc0);
      float xa[16], xb[16];
#pragma unroll
      for (int c = 0; c < 16; ++c) {
        xa[c] = va ? Ls[ra][pc0 + c] : 0.0f;
        xb[c] = vb ? Ls[rb][pc0 + c] : 0.0f;
      }
#pragma unroll
      for (int j = 0; j < 16; ++j) {
        int jj = pc0 + j;
        float dv = (jj < 64) ? __shfl(xa[j], jj) : __shfl(xb[j], jj - 64);
        float di = __builtin_amdgcn_rcpf(dv);
        float ta = (ra > jj) ? xa[j] * di : 0.0f;
        float tb = (rb > jj) ? xb[j] * di : 0.0f;
#pragma unroll
        for (int c = j + 1; c < 16; ++c) {
          int rc = pc0 + c;
          float lc = (rc < 64) ? __shfl(xa[j], rc) : __shfl(xb[j], rc - 64);
          xa[c] -= ta * lc;
          xb[c] -= tb * lc;
        }
      }
#pragma unroll
      for (int c = 0; c < 16; ++c) {
        int rc = pc0 + c;
        float dc = (rc < 64) ? __shfl(xa[c], rc) : __shfl(xb[c], rc - 64);
        float sc = __builtin_amdgcn_rsqf(dc);
        xa[c] *= sc;
        xb[c] *= sc;
      }
      if (va) {
#pragma unroll
        for (int c = 0; c < 16; ++c) Ls[ra][pc0 + c] = xa[c];
      }
      if (vb) {
#pragma unroll
        for (int c = 0; c < 16; ++c) Ls[rb][pc0 + c] = xb[c];
      }
    }
    __syncthreads();

    int s0 = pc0 + 16;
    if (s0 < NB) {
      int r0 = ty * 8, c0 = tx * 8;
      if (r0 >= s0 && c0 >= s0) {
        float acc[8][8];
#pragma unroll
        for (int rr = 0; rr < 8; ++rr) {
          float4 m0 = *(const float4*)&Ls[r0 + rr][c0];
          float4 m1 = *(const float4*)&Ls[r0 + rr][c0 + 4];
          acc[rr][0] = m0.x; acc[rr][1] = m0.y; acc[rr][2] = m0.z; acc[rr][3] = m0.w;
          acc[rr][4] = m1.x; acc[rr][5] = m1.y; acc[rr][6] = m1.z; acc[rr][7] = m1.w;
        }
#pragma unroll
        for (int q = 0; q < 16; ++q) {
          float av[8], bv[8];
#pragma unroll
          for (int rr = 0; rr < 8; ++rr) av[rr] = Ls[r0 + rr][pc0 + q];
#pragma unroll
          for (int cc = 0; cc < 8; ++cc) bv[cc] = Ls[c0 + cc][pc0 + q];
#pragma unroll
          for (int rr = 0; rr < 8; ++rr)
#pragma unroll
            for (int cc = 0; cc < 8; ++cc) acc[rr][cc] -= av[rr] * bv[cc];
        }
#pragma unroll
        for (int rr = 0; rr < 8; ++rr) {
          *(float4*)&Ls[r0 + rr][c0] =
              make_float4(acc[rr][0], acc[rr][1], acc[rr][2], acc[rr][3]);
          *(float4*)&Ls[r0 + rr][c0 + 4] =
              make_float4(acc[rr][4], acc[rr][5], acc[rr][6], acc[rr][7]);
        }
      }
    }
    __syncthreads();
  }
}

__device__ void potrf_store(float* Msrc, float (*Ls)[NB + 1]) {
  int tid = threadIdx.x;
  for (int idx = tid; idx < NB * NB; idx += 256) {
    int i = idx >> 7, j = idx & (NB - 1);
    Msrc[(size_t)i * D + j] = (j <= i) ? Ls[i][j] : 0.0f;
  }
}

__global__ __launch_bounds__(256) void potrf_kernel(float* __restrict__ M, int kb)
{
  __shared__ float Ls[NB][NB + 1];
  int tid = threadIdx.x;
  float* Msrc = M + (size_t)kb * D + kb;
  for (int idx = tid; idx < NB * NB; idx += 256) {
    int i = idx >> 7, j = idx & (NB - 1);
    Ls[i][j] = Msrc[(size_t)i * D + j];
  }
  __syncthreads();
  potrf_factor(Ls);
  potrf_store(Msrc, Ls);
}

// ---------------- syrk0: M = A·A^T + diag(softplus(n)), lower tiles ----------
__global__ __launch_bounds__(256) void syrk0_kernel(
    const float* __restrict__ Asrc, const float* __restrict__ nvec,
    float* __restrict__ Mout)
{
  __shared__ ush Ah[NB][LDP], Al[NB][LDP];
  __shared__ ush Bh[NB][LDP], Bl[NB][LDP];

  int b = blockIdx.x;
  int ti = (int)((sqrtf(8.0f * (float)b + 1.0f) - 1.0f) * 0.5f);
  while ((ti + 1) * (ti + 2) / 2 <= b) ++ti;
  while (ti * (ti + 1) / 2 > b) --ti;
  int tj = b - ti * (ti + 1) / 2;
  int row0 = ti * NB, col0 = tj * NB;

  int tid = threadIdx.x;
  int lane = tid & 63, wid = tid >> 6;
  int wr = wid >> 1, wc = wid & 1;
  int srow = tid >> 1;
  int scg = (tid & 1) * 16;

  f32x4 acc[4][4];
#pragma unroll
  for (int m = 0; m < 4; ++m)
#pragma unroll
    for (int n = 0; n < 4; ++n) acc[m][n] = (f32x4){0.f, 0.f, 0.f, 0.f};

  int lr16 = lane & 15, kof = (lane >> 4) * 8;

  for (int kk = 0; kk < D; kk += KC) {
    const float* pa = Asrc + (size_t)(row0 + srow) * D + kk + scg;
    const float* pb = Asrc + (size_t)(col0 + srow) * D + kk + scg;
    float4 av0 = *(const float4*)(pa + 0), av1 = *(const float4*)(pa + 4);
    float4 av2 = *(const float4*)(pa + 8), av3 = *(const float4*)(pa + 12);
    float4 bv0 = *(const float4*)(pb + 0), bv1 = *(const float4*)(pb + 4);
    float4 bv2 = *(const float4*)(pb + 8), bv3 = *(const float4*)(pb + 12);

    __syncthreads();
    {
      HL p0 = split2(av0.x, av0.y), p1 = split2(av0.z, av0.w);
      HL p2 = split2(av1.x, av1.y), p3 = split2(av1.z, av1.w);
      HL p4 = split2(av2.x, av2.y), p5 = split2(av2.z, av2.w);
      HL p6 = split2(av3.x, av3.y), p7 = split2(av3.z, av3.w);
      uint4v h0 = {p0.h, p1.h, p2.h, p3.h}, l0 = {p0.l, p1.l, p2.l, p3.l};
      uint4v h1 = {p4.h, p5.h, p6.h, p7.h}, l1 = {p4.l, p5.l, p6.l, p7.l};
      *(uint4v*)&Ah[srow][scg] = h0;  *(uint4v*)&Ah[srow][scg + 8] = h1;
      *(uint4v*)&Al[srow][scg] = l0;  *(uint4v*)&Al[srow][scg + 8] = l1;
    }
    {
      HL p0 = split2(bv0.x, bv0.y), p1 = split2(bv0.z, bv0.w);
      HL p2 = split2(bv1.x, bv1.y), p3 = split2(bv1.z, bv1.w);
      HL p4 = split2(bv2.x, bv2.y), p5 = split2(bv2.z, bv2.w);
      HL p6 = split2(bv3.x, bv3.y), p7 = split2(bv3.z, bv3.w);
      uint4v h0 = {p0.h, p1.h, p2.h, p3.h}, l0 = {p0.l, p1.l, p2.l, p3.l};
      uint4v h1 = {p4.h, p5.h, p6.h, p7.h}, l1 = {p4.l, p5.l, p6.l, p7.l};
      *(uint4v*)&Bh[srow][scg] = h0;  *(uint4v*)&Bh[srow][scg + 8] = h1;
      *(uint4v*)&Bl[srow][scg] = l0;  *(uint4v*)&Bl[srow][scg + 8] = l1;
    }
    __syncthreads();

    short8 ah[4], al[4], bh[4], bl[4];
#pragma unroll
    for (int m = 0; m < 4; ++m) {
      int r = wr * 64 + m * 16 + lr16;
      ah[m] = *(const short8*)&Ah[r][kof];
      al[m] = *(const short8*)&Al[r][kof];
    }
#pragma unroll
    for (int n = 0; n < 4; ++n) {
      int c = wc * 64 + n * 16 + lr16;
      bh[n] = *(const short8*)&Bh[c][kof];
      bl[n] = *(const short8*)&Bl[c][kof];
    }
#pragma unroll
    for (int m = 0; m < 4; ++m)
#pragma unroll
      for (int n = 0; n < 4; ++n) {
        acc[m][n] = __builtin_amdgcn_mfma_f32_16x16x32_bf16(ah[m], bh[n], acc[m][n], 0, 0, 0);
        acc[m][n] = __builtin_amdgcn_mfma_f32_16x16x32_bf16(ah[m], bl[n], acc[m][n], 0, 0, 0);
        acc[m][n] = __builtin_amdgcn_mfma_f32_16x16x32_bf16(al[m], bh[n], acc[m][n], 0, 0, 0);
      }
  }

  int cl = lane & 15, rg = (lane >> 4) * 4;
#pragma unroll
  for (int m = 0; m < 4; ++m) {
#pragma unroll
    for (int n = 0; n < 4; ++n) {
      int gi0 = row0 + wr * 64 + m * 16 + rg;
      int gj = col0 + wc * 64 + n * 16 + cl;
#pragma unroll
      for (int r = 0; r < 4; ++r) {
        int gi = gi0 + r;
        float v = acc[m][n][r];
        if (gi == gj) v += softplusf(nvec[gi]);
        Mout[(size_t)gi * D + gj] = v;
      }
    }
  }

  if (ti > tj) {   // mirror-zero the upper tile
    float4 z = make_float4(0.f, 0.f, 0.f, 0.f);
    int zr = tid >> 1;
    int zc0 = (tid & 1) * 64;
    float* zp = Mout + (size_t)(col0 + zr) * D + row0 + zc0;
#pragma unroll
    for (int q = 0; q < 16; ++q) *(float4*)(zp + 4 * q) = z;
  }
}

// ---------------- generalized K=128 GEMM: acc += Arows · Brows^T -------------
__device__ void gemm_bt(const float* __restrict__ Ap, int lda,
                        const float* __restrict__ Bp, int ldb,
                        f32x4 (&acc)[4][4],
                        ush (*Ah)[LDP], ush (*Al)[LDP],
                        ush (*Bh)[LDP], ush (*Bl)[LDP])
{
  int tid = threadIdx.x;
  int lane = tid & 63, wid = tid >> 6;
  int wr = wid >> 1, wc = wid & 1;
  int srow = tid >> 1, scg = (tid & 1) * 16;
  int lr16 = lane & 15, kof = (lane >> 4) * 8;

  for (int kk = 0; kk < NB; kk += KC) {
    const float* pa = Ap + (size_t)srow * lda + kk + scg;
    const float* pb = Bp + (size_t)srow * ldb + kk + scg;
    float4 av0 = *(const float4*)(pa + 0), av1 = *(const float4*)(pa + 4);
    float4 av2 = *(const float4*)(pa + 8), av3 = *(const float4*)(pa + 12);
    float4 bv0 = *(const float4*)(pb + 0), bv1 = *(const float4*)(pb + 4);
    float4 bv2 = *(const float4*)(pb + 8), bv3 = *(const float4*)(pb + 12);

    __syncthreads();
    {
      HL p0 = split2(av0.x, av0.y), p1 = split2(av0.z, av0.w);
      HL p2 = split2(av1.x, av1.y), p3 = split2(av1.z, av1.w);
      HL p4 = split2(av2.x, av2.y), p5 = split2(av2.z, av2.w);
      HL p6 = split2(av3.x, av3.y), p7 = split2(av3.z, av3.w);
      uint4v h0 = {p0.h, p1.h, p2.h, p3.h}, l0 = {p0.l, p1.l, p2.l, p3.l};
      uint4v h1 = {p4.h, p5.h, p6.h, p7.h}, l1 = {p4.l, p5.l, p6.l, p7.l};
      *(uint4v*)&Ah[srow][scg] = h0;  *(uint4v*)&Ah[srow][scg + 8] = h1;
      *(uint4v*)&Al[srow][scg] = l0;  *(uint4v*)&Al[srow][scg + 8] = l1;
    }
    {
      HL p0 = split2(bv0.x, bv0.y), p1 = split2(bv0.z, bv0.w);
      HL p2 = split2(bv1.x, bv1.y), p3 = split2(bv1.z, bv1.w);
      HL p4 = split2(bv2.x, bv2.y), p5 = split2(bv2.z, bv2.w);
      HL p6 = split2(bv3.x, bv3.y), p7 = split2(bv3.z, bv3.w);
      uint4v h0 = {p0.h, p1.h, p2.h, p3.h}, l0 = {p0.l, p1.l, p2.l, p3.l};
      uint4v h1 = {p4.h, p5.h, p6.h, p7.h}, l1 = {p4.l, p5.l, p6.l, p7.l};
      *(uint4v*)&Bh[srow][scg] = h0;  *(uint4v*)&Bh[srow][scg + 8] = h1;
      *(uint4v*)&Bl[srow][scg] = l0;  *(uint4v*)&Bl[srow][scg + 8] = l1;
    }
    __syncthreads();

    short8 ah[4], al[4], bh[4], bl[4];
#pragma unroll
    for (int m = 0; m < 4; ++m) {
      int r = wr * 64 + m * 16 + lr16;
      ah[m] = *(const short8*)&Ah[r][kof];
      al[m] = *(const short8*)&Al[r][kof];
    }
#pragma unroll
    for (int n = 0; n < 4; ++n) {
      int c = wc * 64 + n * 16 + lr16;
      bh[n] = *(const short8*)&Bh[c][kof];
      bl[n] = *(const short8*)&Bl[c][kof];
    }
#pragma unroll
    for (int m = 0; m < 4; ++m)
#pragma unroll
      for (int n = 0; n < 4; ++n) {
        acc[m][n] = __builtin_amdgcn_mfma_f32_16x16x32_bf16(ah[m], bh[n], acc[m][n], 0, 0, 0);
        acc[m][n] = __builtin_amdgcn_mfma_f32_16x16x32_bf16(ah[m], bl[n], acc[m][n], 0, 0, 0);
        acc[m][n] = __builtin_amdgcn_mfma_f32_16x16x32_bf16(al[m], bh[n], acc[m][n], 0, 0, 0);
      }
  }
}

// ---------------- per-column fused step (substitution trsm) -------------------
// bid [0,t1): solver i=k+1+bid — load L(k,k) to LDS, substitute 128 rows of
//   X(i,k), write to M, signal xF[i]. bid 0 continues: SYRK (own X, L2-warm) +
//   potrf(k+1,k+1). No waits on the solver path.
// bid [t1, 2*t1-1): updater i=k+2+... — wait xF[i],xF[k+1]; M(i,k+1) -= X_i·X_{k+1}^T.
// rest: trailing (i,j), j>=k+2 — wait xF[i],xF[j]; M(i,j) -= X_i·X_j^T.
__global__ __launch_bounds__(256) void chol_step3_kernel(
    float* __restrict__ M, unsigned* __restrict__ xF, int k)
{
  __shared__ __align__(16) unsigned char smem[66560];
  ush (*Ah)[LDP] = (ush(*)[LDP])(smem);
  ush (*Al)[LDP] = (ush(*)[LDP])(smem + 10240);
  ush (*Bh)[LDP] = (ush(*)[LDP])(smem + 20480);
  ush (*Bl)[LDP] = (ush(*)[LDP])(smem + 30720);
  float (*Ls)[NB + 1] = (float(*)[NB + 1])smem;
  float* dinv = (float*)(smem + NB * (NB + 1) * 4);

  int t1 = NT - 1 - k;
  int bid = blockIdx.x;
  int tid = threadIdx.x;
  int lane = tid & 63, wid = tid >> 6;
  int wr = wid >> 1, wc = wid & 1;
  int cl = lane & 15, rg = (lane >> 4) * 4;

  if (bid < t1) {
    int i = k + 1 + bid;
    // load L(k,k) into LDS (upper already zeroed by potrf_store)
    const float* Lsrc = M + (size_t)(k * NB) * D + k * NB;
    for (int idx = tid; idx < NB * NB; idx += 256) {
      int r = idx >> 7, c = idx & (NB - 1);
      Ls[r][c] = Lsrc[(size_t)r * D + c];
    }
    __syncthreads();
    if (tid < NB) dinv[tid] = 1.0f / Ls[tid][tid];
    __syncthreads();
    int w = tid >> 6;
    for (int pass = 0; pass < 16; ++pass) {
      size_t r0 = (size_t)(i * NB + pass * 8 + w * 2);
      float* p0 = M + r0 * D + k * NB;
      float* p1 = p0 + D;
      float x0l = p0[lane], x0h = p0[64 + lane];
      float x1l = p1[lane], x1h = p1[64 + lane];
      for (int p = 0; p < 64; ++p) {
        float dv = dinv[p];
        float xp0 = __shfl(x0l, p) * dv;
        float xp1 = __shfl(x1l, p) * dv;
        float Llo = Ls[lane][p];
        float Lhi = Ls[64 + lane][p];
        if (lane == p)      { x0l = xp0; x1l = xp1; }
        else if (lane > p)  { x0l -= xp0 * Llo; x1l -= xp1 * Llo; }
        x0h -= xp0 * Lhi;
        x1h -= xp1 * Lhi;
      }
      for (int p = 64; p < NB; ++p) {
        int qq = p - 64;
        float dv = dinv[p];
        float xp0 = __shfl(x0h, qq) * dv;
        float xp1 = __shfl(x1h, qq) * dv;
        float Lhi = Ls[64 + lane][p];
        if (lane == qq)      { x0h = xp0; x1h = xp1; }
        else if (lane > qq)  { x0h -= xp0 * Lhi; x1h -= xp1 * Lhi; }
      }
      p0[lane] = x0l; p0[64 + lane] = x0h;
      p1[lane] = x1l; p1[64 + lane] = x1h;
    }
    signal_add(xF + i);   // __syncthreads inside: all X stores issued + fenced

    if (bid == 0) {
      // SYRK: S = X(k+1,k)·X(k+1,k)^T (re-read own write, L2-warm)
      float* Xt = M + (size_t)(i * NB) * D + k * NB;
      f32x4 acc2[4][4];
#pragma unroll
      for (int m = 0; m < 4; ++m)
#pragma unroll
        for (int n = 0; n < 4; ++n) acc2[m][n] = (f32x4){0.f, 0.f, 0.f, 0.f};
      gemm_bt(Xt, D, Xt, D, acc2, Ah, Al, Bh, Bl);
      __syncthreads();   // staging LDS reads done before smem reuse as Ls
      float* Mt = M + (size_t)(i * NB) * D + i * NB;
#pragma unroll
      for (int m = 0; m < 4; ++m)
#pragma unroll
        for (int n = 0; n < 4; ++n) {
          int li0 = wr * 64 + m * 16 + rg;
          int lj = wc * 64 + n * 16 + cl;
#pragma unroll
          for (int r = 0; r < 4; ++r)
            Ls[li0 + r][lj] = Mt[(size_t)(li0 + r) * D + lj] - acc2[m][n][r];
        }
      __syncthreads();
      potrf_factor(Ls);
      potrf_store(Mt, Ls);
    }
    return;
  }
  bid -= t1;
  int nu = t1 - 1;
  if (bid < nu) {
    // updater: M(i,k+1) -= X(i,k)·X(k+1,k)^T  (prepares next column's X0)
    int i = k + 2 + bid;
    wait_ge(xF + i, (unsigned)(k + 1));
    wait_ge(xF + (k + 1), (unsigned)(k + 1));
    f32x4 acc[4][4];
#pragma unroll
    for (int m = 0; m < 4; ++m)
#pragma unroll
      for (int n = 0; n < 4; ++n) acc[m][n] = (f32x4){0.f, 0.f, 0.f, 0.f};
    gemm_bt(M + (size_t)(i * NB) * D + k * NB, D,
            M + (size_t)((k + 1) * NB) * D + k * NB, D, acc, Ah, Al, Bh, Bl);
    float* Mt = M + (size_t)(i * NB) * D + (k + 1) * NB;
#pragma unroll
    for (int m = 0; m < 4; ++m)
#pragma unroll
      for (int n = 0; n < 4; ++n) {
        int li0 = wr * 64 + m * 16 + rg;
        int lj = wc * 64 + n * 16 + cl;
#pragma unroll
        for (int r = 0; r < 4; ++r)
          Mt[(size_t)(li0 + r) * D + lj] -= acc[m][n][r];
      }
    return;
  }
  bid -= nu;
  // trailing tile (i,j), k+2 <= j <= i <= NT-1
  int s = bid;
  int tp = (int)((sqrtf(8.0f * (float)s + 1.0f) - 1.0f) * 0.5f);
  while ((tp + 1) * (tp + 2) / 2 <= s) ++tp;
  while (tp * (tp + 1) / 2 > s) --tp;
  int tq = s - tp * (tp + 1) / 2;
  int i = k + 2 + tp, j = k + 2 + tq;

  wait_ge(xF + i, (unsigned)(k + 1));
  if (j != i) wait_ge(xF + j, (unsigned)(k + 1));

  f32x4 acc[4][4];
#pragma unroll
  for (int m = 0; m < 4; ++m)
#pragma unroll
    for (int n = 0; n < 4; ++n) acc[m][n] = (f32x4){0.f, 0.f, 0.f, 0.f};
  gemm_bt(M + (size_t)(i * NB) * D + k * NB, D,
          M + (size_t)(j * NB) * D + k * NB, D, acc, Ah, Al, Bh, Bl);

  float* Mt = M + (size_t)(i * NB) * D + j * NB;
#pragma unroll
  for (int m = 0; m < 4; ++m)
#pragma unroll
    for (int n = 0; n < 4; ++n) {
      int li0 = wr * 64 + m * 16 + rg;
      int lj = wc * 64 + n * 16 + cl;
#pragma unroll
      for (int r = 0; r < 4; ++r)
        Mt[(size_t)(li0 + r) * D + lj] -= acc[m][n][r];
    }
}

extern "C" void kernel_launch(void* const* d_in, const int* in_sizes, int n_in,
                              void* d_out, int out_size, void* d_ws, size_t ws_size,
                              hipStream_t stream)
{
  (void)in_sizes; (void)n_in; (void)ws_size; (void)out_size;
  const float* A  = (const float*)d_in[0];
  const float* nv = (const float*)d_in[1];
  float* M = (float*)d_out;
  unsigned* xF = (unsigned*)d_ws;

  hipMemsetAsync(d_ws, 0, NT * sizeof(unsigned), stream);

  syrk0_kernel<<<NT * (NT + 1) / 2, 256, 0, stream>>>(A, nv, M);
  potrf_kernel<<<1, 256, 0, stream>>>(M, 0);

  for (int k = 0; k <= 30; ++k) {
    int t1 = NT - 1 - k;
    int nu = t1 - 1;
    int t2 = t1 - 1;
    int C2 = (t2 > 0) ? t2 * (t2 + 1) / 2 : 0;
    int grid = t1 + nu + C2;
    chol_step3_kernel<<<grid, 256, 0, stream>>>(M, xF, k);
  }
}

// Round 13
// 6283.371 us; speedup vs baseline: 1.4581x; 1.4581x over previous
//
#include <hip/hip_runtime.h>
#include <math.h>

#define D 4096
#define NB 128
#define KC 32
#define NT (D / NB)      // 32 tiles per side
#define LDP 40           // padded LDS row stride in bf16 elems (80 B)

typedef __attribute__((ext_vector_type(8))) short short8;
typedef __attribute__((ext_vector_type(4))) float f32x4;
typedef __attribute__((ext_vector_type(4))) unsigned int uint4v;
typedef unsigned short ush;

__device__ __forceinline__ float softplusf(float x) {
  return fmaxf(x, 0.0f) + log1pf(expf(-fabsf(x)));
}

struct HL { unsigned int h, l; };

__device__ __forceinline__ HL split2(float x0, float x1) {
  unsigned int b0 = __float_as_uint(x0), b1 = __float_as_uint(x1);
  unsigned int h0 = b0 & 0xFFFF0000u, h1 = b1 & 0xFFFF0000u;
  float r0 = x0 - __uint_as_float(h0);
  float r1 = x1 - __uint_as_float(h1);
  HL out;
  out.h = h1 | (h0 >> 16);
  out.l = (__float_as_uint(r1) & 0xFFFF0000u) | (__float_as_uint(r0) >> 16);
  return out;
}

// scalar split: returns hi16, lo16
__device__ __forceinline__ void split1(float x, ush& h, ush& l) {
  unsigned int b = __float_as_uint(x);
  unsigned int hb = b & 0xFFFF0000u;
  float r = x - __uint_as_float(hb);
  h = (ush)(hb >> 16);
  l = (ush)(__float_as_uint(r) >> 16);
}

// ---------------- in-LDS potrf of a 128x128 tile (rcp chain) -----------------
__device__ void potrf_factor(float (*Ls)[NB + 1]) {
  int tid = threadIdx.x;
  int lane = tid & 63, wid = tid >> 6;
  int tx = tid & 15, ty = tid >> 4;

  for (int pp = 0; pp < 8; ++pp) {
    int pc0 = pp * 16;
    if (wid == 0) {
      int ra = lane, rb = lane + 64;
      bool va = (ra >= pc0), vb = (rb >= pc0);
      float xa[16], xb[16];
#pragma unroll
      for (int c = 0; c < 16; ++c) {
        xa[c] = va ? Ls[ra][pc0 + c] : 0.0f;
        xb[c] = vb ? Ls[rb][pc0 + c] : 0.0f;
      }
#pragma unroll
      for (int j = 0; j < 16; ++j) {
        int jj = pc0 + j;
        float dv = (jj < 64) ? __shfl(xa[j], jj) : __shfl(xb[j], jj - 64);
        float di = __builtin_amdgcn_rcpf(dv);
        float ta = (ra > jj) ? xa[j] * di : 0.0f;
        float tb = (rb > jj) ? xb[j] * di : 0.0f;
#pragma unroll
        for (int c = j + 1; c < 16; ++c) {
          int rc = pc0 + c;
          float lc = (rc < 64) ? __shfl(xa[j], rc) : __shfl(xb[j], rc - 64);
          xa[c] -= ta * lc;
          xb[c] -= tb * lc;
        }
      }
#pragma unroll
      for (int c = 0; c < 16; ++c) {
        int rc = pc0 + c;
        float dc = (rc < 64) ? __shfl(xa[c], rc) : __shfl(xb[c], rc - 64);
        float sc = __builtin_amdgcn_rsqf(dc);
        xa[c] *= sc;
        xb[c] *= sc;
      }
      if (va) {
#pragma unroll
        for (int c = 0; c < 16; ++c) Ls[ra][pc0 + c] = xa[c];
      }
      if (vb) {
#pragma unroll
        for (int c = 0; c < 16; ++c) Ls[rb][pc0 + c] = xb[c];
      }
    }
    __syncthreads();

    int s0 = pc0 + 16;
    if (s0 < NB) {
      int r0 = ty * 8, c0 = tx * 8;
      if (r0 >= s0 && c0 >= s0) {
        float acc[8][8];
#pragma unroll
        for (int rr = 0; rr < 8; ++rr) {
          float4 m0 = *(const float4*)&Ls[r0 + rr][c0];
          float4 m1 = *(const float4*)&Ls[r0 + rr][c0 + 4];
          acc[rr][0] = m0.x; acc[rr][1] = m0.y; acc[rr][2] = m0.z; acc[rr][3] = m0.w;
          acc[rr][4] = m1.x; acc[rr][5] = m1.y; acc[rr][6] = m1.z; acc[rr][7] = m1.w;
        }
#pragma unroll
        for (int q = 0; q < 16; ++q) {
          float av[8], bv[8];
#pragma unroll
          for (int rr = 0; rr < 8; ++rr) av[rr] = Ls[r0 + rr][pc0 + q];
#pragma unroll
          for (int cc = 0; cc < 8; ++cc) bv[cc] = Ls[c0 + cc][pc0 + q];
#pragma unroll
          for (int rr = 0; rr < 8; ++rr)
#pragma unroll
            for (int cc = 0; cc < 8; ++cc) acc[rr][cc] -= av[rr] * bv[cc];
        }
#pragma unroll
        for (int rr = 0; rr < 8; ++rr) {
          *(float4*)&Ls[r0 + rr][c0] =
              make_float4(acc[rr][0], acc[rr][1], acc[rr][2], acc[rr][3]);
          *(float4*)&Ls[r0 + rr][c0 + 4] =
              make_float4(acc[rr][4], acc[rr][5], acc[rr][6], acc[rr][7]);
        }
      }
    }
    __syncthreads();
  }
}

__device__ void potrf_store(float* Msrc, float (*Ls)[NB + 1]) {
  int tid = threadIdx.x;
  for (int idx = tid; idx < NB * NB; idx += 256) {
    int i = idx >> 7, j = idx & (NB - 1);
    Msrc[(size_t)i * D + j] = (j <= i) ? Ls[i][j] : 0.0f;
  }
}

__global__ __launch_bounds__(256) void potrf_kernel(float* __restrict__ M, int kb)
{
  __shared__ float Ls[NB][NB + 1];
  int tid = threadIdx.x;
  float* Msrc = M + (size_t)kb * D + kb;
  for (int idx = tid; idx < NB * NB; idx += 256) {
    int i = idx >> 7, j = idx & (NB - 1);
    Ls[i][j] = Msrc[(size_t)i * D + j];
  }
  __syncthreads();
  potrf_factor(Ls);
  potrf_store(Msrc, Ls);
}

// ---------------- syrk0: M = A·A^T + diag(softplus(n)), lower tiles ----------
__global__ __launch_bounds__(256) void syrk0_kernel(
    const float* __restrict__ Asrc, const float* __restrict__ nvec,
    float* __restrict__ Mout)
{
  __shared__ ush Ah[NB][LDP], Al[NB][LDP];
  __shared__ ush Bh[NB][LDP], Bl[NB][LDP];

  int b = blockIdx.x;
  int ti = (int)((sqrtf(8.0f * (float)b + 1.0f) - 1.0f) * 0.5f);
  while ((ti + 1) * (ti + 2) / 2 <= b) ++ti;
  while (ti * (ti + 1) / 2 > b) --ti;
  int tj = b - ti * (ti + 1) / 2;
  int row0 = ti * NB, col0 = tj * NB;

  int tid = threadIdx.x;
  int lane = tid & 63, wid = tid >> 6;
  int wr = wid >> 1, wc = wid & 1;
  int srow = tid >> 1;
  int scg = (tid & 1) * 16;

  f32x4 acc[4][4];
#pragma unroll
  for (int m = 0; m < 4; ++m)
#pragma unroll
    for (int n = 0; n < 4; ++n) acc[m][n] = (f32x4){0.f, 0.f, 0.f, 0.f};

  int lr16 = lane & 15, kof = (lane >> 4) * 8;

  for (int kk = 0; kk < D; kk += KC) {
    const float* pa = Asrc + (size_t)(row0 + srow) * D + kk + scg;
    const float* pb = Asrc + (size_t)(col0 + srow) * D + kk + scg;
    float4 av0 = *(const float4*)(pa + 0), av1 = *(const float4*)(pa + 4);
    float4 av2 = *(const float4*)(pa + 8), av3 = *(const float4*)(pa + 12);
    float4 bv0 = *(const float4*)(pb + 0), bv1 = *(const float4*)(pb + 4);
    float4 bv2 = *(const float4*)(pb + 8), bv3 = *(const float4*)(pb + 12);

    __syncthreads();
    {
      HL p0 = split2(av0.x, av0.y), p1 = split2(av0.z, av0.w);
      HL p2 = split2(av1.x, av1.y), p3 = split2(av1.z, av1.w);
      HL p4 = split2(av2.x, av2.y), p5 = split2(av2.z, av2.w);
      HL p6 = split2(av3.x, av3.y), p7 = split2(av3.z, av3.w);
      uint4v h0 = {p0.h, p1.h, p2.h, p3.h}, l0 = {p0.l, p1.l, p2.l, p3.l};
      uint4v h1 = {p4.h, p5.h, p6.h, p7.h}, l1 = {p4.l, p5.l, p6.l, p7.l};
      *(uint4v*)&Ah[srow][scg] = h0;  *(uint4v*)&Ah[srow][scg + 8] = h1;
      *(uint4v*)&Al[srow][scg] = l0;  *(uint4v*)&Al[srow][scg + 8] = l1;
    }
    {
      HL p0 = split2(bv0.x, bv0.y), p1 = split2(bv0.z, bv0.w);
      HL p2 = split2(bv1.x, bv1.y), p3 = split2(bv1.z, bv1.w);
      HL p4 = split2(bv2.x, bv2.y), p5 = split2(bv2.z, bv2.w);
      HL p6 = split2(bv3.x, bv3.y), p7 = split2(bv3.z, bv3.w);
      uint4v h0 = {p0.h, p1.h, p2.h, p3.h}, l0 = {p0.l, p1.l, p2.l, p3.l};
      uint4v h1 = {p4.h, p5.h, p6.h, p7.h}, l1 = {p4.l, p5.l, p6.l, p7.l};
      *(uint4v*)&Bh[srow][scg] = h0;  *(uint4v*)&Bh[srow][scg + 8] = h1;
      *(uint4v*)&Bl[srow][scg] = l0;  *(uint4v*)&Bl[srow][scg + 8] = l1;
    }
    __syncthreads();

    short8 ah[4], al[4], bh[4], bl[4];
#pragma unroll
    for (int m = 0; m < 4; ++m) {
      int r = wr * 64 + m * 16 + lr16;
      ah[m] = *(const short8*)&Ah[r][kof];
      al[m] = *(const short8*)&Al[r][kof];
    }
#pragma unroll
    for (int n = 0; n < 4; ++n) {
      int c = wc * 64 + n * 16 + lr16;
      bh[n] = *(const short8*)&Bh[c][kof];
      bl[n] = *(const short8*)&Bl[c][kof];
    }
#pragma unroll
    for (int m = 0; m < 4; ++m)
#pragma unroll
      for (int n = 0; n < 4; ++n) {
        acc[m][n] = __builtin_amdgcn_mfma_f32_16x16x32_bf16(ah[m], bh[n], acc[m][n], 0, 0, 0);
        acc[m][n] = __builtin_amdgcn_mfma_f32_16x16x32_bf16(ah[m], bl[n], acc[m][n], 0, 0, 0);
        acc[m][n] = __builtin_amdgcn_mfma_f32_16x16x32_bf16(al[m], bh[n], acc[m][n], 0, 0, 0);
      }
  }

  int cl = lane & 15, rg = (lane >> 4) * 4;
#pragma unroll
  for (int m = 0; m < 4; ++m) {
#pragma unroll
    for (int n = 0; n < 4; ++n) {
      int gi0 = row0 + wr * 64 + m * 16 + rg;
      int gj = col0 + wc * 64 + n * 16 + cl;
#pragma unroll
      for (int r = 0; r < 4; ++r) {
        int gi = gi0 + r;
        float v = acc[m][n][r];
        if (gi == gj) v += softplusf(nvec[gi]);
        Mout[(size_t)gi * D + gj] = v;
      }
    }
  }

  if (ti > tj) {   // mirror-zero the upper tile
    float4 z = make_float4(0.f, 0.f, 0.f, 0.f);
    int zr = tid >> 1;
    int zc0 = (tid & 1) * 64;
    float* zp = Mout + (size_t)(col0 + zr) * D + row0 + zc0;
#pragma unroll
    for (int q = 0; q < 16; ++q) *(float4*)(zp + 4 * q) = z;
  }
}

// ---------------- trsm: 64 rows/block, optional bf16 shadow write ------------
// Solves X·L(kb,kb)^T = M21 for rows [kb+NB, D), 64 rows per block.
template <bool SH>
__global__ __launch_bounds__(256) void trsm_kernel(
    float* __restrict__ M, int kb, ush* __restrict__ shH, ush* __restrict__ shL)
{
  __shared__ float Ls[NB][NB + 1];
  __shared__ float dinv[NB];
  int tid = threadIdx.x;
  const float* Lsrc = M + (size_t)kb * D + kb;
  for (int idx = tid; idx < NB * NB; idx += 256) {
    int i = idx >> 7, j = idx & (NB - 1);
    Ls[i][j] = Lsrc[(size_t)i * D + j];   // upper already zeroed by potrf_store
  }
  __syncthreads();
  if (tid < NB) dinv[tid] = 1.0f / Ls[tid][tid];
  __syncthreads();
  int lane = tid & 63, w = tid >> 6;
  size_t base = (size_t)(kb + NB) + (size_t)blockIdx.x * 64;
  for (int pass = 0; pass < 8; ++pass) {
    size_t r0 = base + pass * 8 + w * 2;
    float* p0 = M + r0 * D + kb;
    float* p1 = p0 + D;
    float x0l = p0[lane], x0h = p0[64 + lane];
    float x1l = p1[lane], x1h = p1[64 + lane];
    for (int p = 0; p < 64; ++p) {
      float dv = dinv[p];
      float xp0 = __shfl(x0l, p) * dv;
      float xp1 = __shfl(x1l, p) * dv;
      float Llo = Ls[lane][p];
      float Lhi = Ls[64 + lane][p];
      if (lane == p)      { x0l = xp0; x1l = xp1; }
      else if (lane > p)  { x0l -= xp0 * Llo; x1l -= xp1 * Llo; }
      x0h -= xp0 * Lhi;
      x1h -= xp1 * Lhi;
    }
    for (int p = 64; p < NB; ++p) {
      int q = p - 64;
      float dv = dinv[p];
      float xp0 = __shfl(x0h, q) * dv;
      float xp1 = __shfl(x1h, q) * dv;
      float Lhi = Ls[64 + lane][p];
      if (lane == q)      { x0h = xp0; x1h = xp1; }
      else if (lane > q)  { x0h -= xp0 * Lhi; x1h -= xp1 * Lhi; }
    }
    p0[lane] = x0l; p0[64 + lane] = x0h;
    p1[lane] = x1l; p1[64 + lane] = x1h;
    if (SH) {
      ush h, l;
      split1(x0l, h, l);
      shH[r0 * NB + lane] = h;        shL[r0 * NB + lane] = l;
      split1(x0h, h, l);
      shH[r0 * NB + 64 + lane] = h;   shL[r0 * NB + 64 + lane] = l;
      split1(x1l, h, l);
      shH[(r0 + 1) * NB + lane] = h;      shL[(r0 + 1) * NB + lane] = l;
      split1(x1h, h, l);
      shH[(r0 + 1) * NB + 64 + lane] = h; shL[(r0 + 1) * NB + 64 + lane] = l;
    }
  }
}

// ---------------- K=128 GEMM from fp32 rows (fallback path) ------------------
__device__ void gemm_bt(const float* __restrict__ Ap, const float* __restrict__ Bp,
                        f32x4 (&acc)[4][4],
                        ush (*Ah)[LDP], ush (*Al)[LDP],
                        ush (*Bh)[LDP], ush (*Bl)[LDP])
{
  int tid = threadIdx.x;
  int lane = tid & 63, wid = tid >> 6;
  int wr = wid >> 1, wc = wid & 1;
  int srow = tid >> 1, scg = (tid & 1) * 16;
  int lr16 = lane & 15, kof = (lane >> 4) * 8;

  for (int kk = 0; kk < NB; kk += KC) {
    const float* pa = Ap + (size_t)srow * D + kk + scg;
    const float* pb = Bp + (size_t)srow * D + kk + scg;
    float4 av0 = *(const float4*)(pa + 0), av1 = *(const float4*)(pa + 4);
    float4 av2 = *(const float4*)(pa + 8), av3 = *(const float4*)(pa + 12);
    float4 bv0 = *(const float4*)(pb + 0), bv1 = *(const float4*)(pb + 4);
    float4 bv2 = *(const float4*)(pb + 8), bv3 = *(const float4*)(pb + 12);

    __syncthreads();
    {
      HL p0 = split2(av0.x, av0.y), p1 = split2(av0.z, av0.w);
      HL p2 = split2(av1.x, av1.y), p3 = split2(av1.z, av1.w);
      HL p4 = split2(av2.x, av2.y), p5 = split2(av2.z, av2.w);
      HL p6 = split2(av3.x, av3.y), p7 = split2(av3.z, av3.w);
      uint4v h0 = {p0.h, p1.h, p2.h, p3.h}, l0 = {p0.l, p1.l, p2.l, p3.l};
      uint4v h1 = {p4.h, p5.h, p6.h, p7.h}, l1 = {p4.l, p5.l, p6.l, p7.l};
      *(uint4v*)&Ah[srow][scg] = h0;  *(uint4v*)&Ah[srow][scg + 8] = h1;
      *(uint4v*)&Al[srow][scg] = l0;  *(uint4v*)&Al[srow][scg + 8] = l1;
    }
    {
      HL p0 = split2(bv0.x, bv0.y), p1 = split2(bv0.z, bv0.w);
      HL p2 = split2(bv1.x, bv1.y), p3 = split2(bv1.z, bv1.w);
      HL p4 = split2(bv2.x, bv2.y), p5 = split2(bv2.z, bv2.w);
      HL p6 = split2(bv3.x, bv3.y), p7 = split2(bv3.z, bv3.w);
      uint4v h0 = {p0.h, p1.h, p2.h, p3.h}, l0 = {p0.l, p1.l, p2.l, p3.l};
      uint4v h1 = {p4.h, p5.h, p6.h, p7.h}, l1 = {p4.l, p5.l, p6.l, p7.l};
      *(uint4v*)&Bh[srow][scg] = h0;  *(uint4v*)&Bh[srow][scg + 8] = h1;
      *(uint4v*)&Bl[srow][scg] = l0;  *(uint4v*)&Bl[srow][scg + 8] = l1;
    }
    __syncthreads();

    short8 ah[4], al[4], bh[4], bl[4];
#pragma unroll
    for (int m = 0; m < 4; ++m) {
      int r = wr * 64 + m * 16 + lr16;
      ah[m] = *(const short8*)&Ah[r][kof];
      al[m] = *(const short8*)&Al[r][kof];
    }
#pragma unroll
    for (int n = 0; n < 4; ++n) {
      int c = wc * 64 + n * 16 + lr16;
      bh[n] = *(const short8*)&Bh[c][kof];
      bl[n] = *(const short8*)&Bl[c][kof];
    }
#pragma unroll
    for (int m = 0; m < 4; ++m)
#pragma unroll
      for (int n = 0; n < 4; ++n) {
        acc[m][n] = __builtin_amdgcn_mfma_f32_16x16x32_bf16(ah[m], bh[n], acc[m][n], 0, 0, 0);
        acc[m][n] = __builtin_amdgcn_mfma_f32_16x16x32_bf16(ah[m], bl[n], acc[m][n], 0, 0, 0);
        acc[m][n] = __builtin_amdgcn_mfma_f32_16x16x32_bf16(al[m], bh[n], acc[m][n], 0, 0, 0);
      }
  }
}

// ---------------- K=128 GEMM from bf16 shadow rows ---------------------------
__device__ void gemm_bt_sh(const ush* __restrict__ AhG, const ush* __restrict__ AlG,
                           const ush* __restrict__ BhG, const ush* __restrict__ BlG,
                           f32x4 (&acc)[4][4],
                           ush (*Ah)[LDP], ush (*Al)[LDP],
                           ush (*Bh)[LDP], ush (*Bl)[LDP])
{
  int tid = threadIdx.x;
  int lane = tid & 63, wid = tid >> 6;
  int wr = wid >> 1, wc = wid & 1;
  int srow = tid >> 1, scg = (tid & 1) * 16;
  int lr16 = lane & 15, kof = (lane >> 4) * 8;

  for (int kk = 0; kk < NB; kk += KC) {
    const ush* pah = AhG + (size_t)srow * NB + kk + scg;
    const ush* pal = AlG + (size_t)srow * NB + kk + scg;
    const ush* pbh = BhG + (size_t)srow * NB + kk + scg;
    const ush* pbl = BlG + (size_t)srow * NB + kk + scg;
    short8 vah0 = *(const short8*)(pah), vah1 = *(const short8*)(pah + 8);
    short8 val0 = *(const short8*)(pal), val1 = *(const short8*)(pal + 8);
    short8 vbh0 = *(const short8*)(pbh), vbh1 = *(const short8*)(pbh + 8);
    short8 vbl0 = *(const short8*)(pbl), vbl1 = *(const short8*)(pbl + 8);

    __syncthreads();
    *(short8*)&Ah[srow][scg] = vah0;  *(short8*)&Ah[srow][scg + 8] = vah1;
    *(short8*)&Al[srow][scg] = val0;  *(short8*)&Al[srow][scg + 8] = val1;
    *(short8*)&Bh[srow][scg] = vbh0;  *(short8*)&Bh[srow][scg + 8] = vbh1;
    *(short8*)&Bl[srow][scg] = vbl0;  *(short8*)&Bl[srow][scg + 8] = vbl1;
    __syncthreads();

    short8 ah[4], al[4], bh[4], bl[4];
#pragma unroll
    for (int m = 0; m < 4; ++m) {
      int r = wr * 64 + m * 16 + lr16;
      ah[m] = *(const short8*)&Ah[r][kof];
      al[m] = *(const short8*)&Al[r][kof];
    }
#pragma unroll
    for (int n = 0; n < 4; ++n) {
      int c = wc * 64 + n * 16 + lr16;
      bh[n] = *(const short8*)&Bh[c][kof];
      bl[n] = *(const short8*)&Bl[c][kof];
    }
#pragma unroll
    for (int m = 0; m < 4; ++m)
#pragma unroll
      for (int n = 0; n < 4; ++n) {
        acc[m][n] = __builtin_amdgcn_mfma_f32_16x16x32_bf16(ah[m], bh[n], acc[m][n], 0, 0, 0);
        acc[m][n] = __builtin_amdgcn_mfma_f32_16x16x32_bf16(ah[m], bl[n], acc[m][n], 0, 0, 0);
        acc[m][n] = __builtin_amdgcn_mfma_f32_16x16x32_bf16(al[m], bh[n], acc[m][n], 0, 0, 0);
      }
  }
}

// ---------------- trailing update; block 0 fuses potrf of next diag ----------
template <bool SH>
__global__ __launch_bounds__(256) void syrk1_kernel(
    float* __restrict__ M, int kb,
    const ush* __restrict__ shH, const ush* __restrict__ shL)
{
  __shared__ __align__(16) unsigned char smem[66560];
  ush (*Ah)[LDP] = (ush(*)[LDP])(smem);
  ush (*Al)[LDP] = (ush(*)[LDP])(smem + 10240);
  ush (*Bh)[LDP] = (ush(*)[LDP])(smem + 20480);
  ush (*Bl)[LDP] = (ush(*)[LDP])(smem + 30720);
  float (*Ls)[NB + 1] = (float(*)[NB + 1])smem;

  float* Mout = M + (size_t)(kb + NB) * D + (kb + NB);     // trailing matrix
  const float* Xsrc = M + (size_t)(kb + NB) * D + kb;      // solved panel (fp32)

  int s = blockIdx.x;
  int ti = (int)((sqrtf(8.0f * (float)s + 1.0f) - 1.0f) * 0.5f);
  while ((ti + 1) * (ti + 2) / 2 <= s) ++ti;
  while (ti * (ti + 1) / 2 > s) --ti;
  int tj = s - ti * (ti + 1) / 2;
  int row0 = ti * NB, col0 = tj * NB;

  int tid = threadIdx.x;
  int lane = tid & 63, wid = tid >> 6;
  int wr = wid >> 1, wc = wid & 1;
  int cl = lane & 15, rg = (lane >> 4) * 4;

  f32x4 acc[4][4];
#pragma unroll
  for (int m = 0; m < 4; ++m)
#pragma unroll
    for (int n = 0; n < 4; ++n) acc[m][n] = (f32x4){0.f, 0.f, 0.f, 0.f};

  if (SH) {
    size_t ra = (size_t)(kb + NB + row0) * NB;
    size_t rb = (size_t)(kb + NB + col0) * NB;
    gemm_bt_sh(shH + ra, shL + ra, shH + rb, shL + rb, acc, Ah, Al, Bh, Bl);
  } else {
    gemm_bt(Xsrc + (size_t)row0 * D, Xsrc + (size_t)col0 * D, acc, Ah, Al, Bh, Bl);
  }

  if (s == 0) {
    // fused potrf of next diag tile
    __syncthreads();   // staging LDS reads done before smem reuse as Ls
#pragma unroll
    for (int m = 0; m < 4; ++m)
#pragma unroll
      for (int n = 0; n < 4; ++n) {
        int li0 = wr * 64 + m * 16 + rg;
        int lj = wc * 64 + n * 16 + cl;
#pragma unroll
        for (int r = 0; r < 4; ++r) {
          int li = li0 + r;
          Ls[li][lj] = Mout[(size_t)li * D + lj] - acc[m][n][r];
        }
      }
    __syncthreads();
    potrf_factor(Ls);
    potrf_store(Mout, Ls);
    return;
  }

#pragma unroll
  for (int m = 0; m < 4; ++m) {
#pragma unroll
    for (int n = 0; n < 4; ++n) {
      int gi0 = row0 + wr * 64 + m * 16 + rg;
      int gj = col0 + wc * 64 + n * 16 + cl;
#pragma unroll
      for (int r = 0; r < 4; ++r) {
        int gi = gi0 + r;
        Mout[(size_t)gi * D + gj] -= acc[m][n][r];
      }
    }
  }
}

extern "C" void kernel_launch(void* const* d_in, const int* in_sizes, int n_in,
                              void* d_out, int out_size, void* d_ws, size_t ws_size,
                              hipStream_t stream)
{
  (void)in_sizes; (void)n_in; (void)out_size;
  const float* A  = (const float*)d_in[0];
  const float* nv = (const float*)d_in[1];
  float* M = (float*)d_out;

  const size_t shadow_bytes = (size_t)2 * D * NB * sizeof(ush);  // 2 MB
  bool sh = (ws_size >= shadow_bytes);
  ush* shH = (ush*)d_ws;
  ush* shL = shH + (size_t)D * NB;

  syrk0_kernel<<<NT * (NT + 1) / 2, 256, 0, stream>>>(A, nv, M);
  potrf_kernel<<<1, 256, 0, stream>>>(M, 0);

  for (int k = 0; k <= 30; ++k) {
    int kb = k * NB;
    int T = D - kb - NB;
    int t = T / NB;
    if (sh) {
      trsm_kernel<true><<<T / 64, 256, 0, stream>>>(M, kb, shH, shL);
      syrk1_kernel<true><<<t * (t + 1) / 2, 256, 0, stream>>>(M, kb, shH, shL);
    } else {
      trsm_kernel<false><<<T / 64, 256, 0, stream>>>(M, kb, nullptr, nullptr);
      syrk1_kernel<false><<<t * (t + 1) / 2, 256, 0, stream>>>(M, kb, nullptr, nullptr);
    }
  }
}

// Round 14
// 3702.827 us; speedup vs baseline: 2.4743x; 1.6969x over previous
//
#include <hip/hip_runtime.h>
#include <math.h>

#define D 4096
#define NB 128
#define KC 32
#define NT (D / NB)      // 32 tiles per side
#define LDP 40           // padded LDS row stride in bf16 elems (80 B)

typedef __attribute__((ext_vector_type(8))) short short8;
typedef __attribute__((ext_vector_type(4))) float f32x4;
typedef __attribute__((ext_vector_type(4))) unsigned int uint4v;
typedef unsigned short ush;

__device__ __forceinline__ float softplusf(float x) {
  return fmaxf(x, 0.0f) + log1pf(expf(-fabsf(x)));
}

struct HL { unsigned int h, l; };

__device__ __forceinline__ HL split2(float x0, float x1) {
  unsigned int b0 = __float_as_uint(x0), b1 = __float_as_uint(x1);
  unsigned int h0 = b0 & 0xFFFF0000u, h1 = b1 & 0xFFFF0000u;
  float r0 = x0 - __uint_as_float(h0);
  float r1 = x1 - __uint_as_float(h1);
  HL out;
  out.h = h1 | (h0 >> 16);
  out.l = (__float_as_uint(r1) & 0xFFFF0000u) | (__float_as_uint(r0) >> 16);
  return out;
}

__device__ __forceinline__ void split1(float x, ush& h, ush& l) {
  unsigned int b = __float_as_uint(x);
  unsigned int hb = b & 0xFFFF0000u;
  float r = x - __uint_as_float(hb);
  h = (ush)(hb >> 16);
  l = (ush)(__float_as_uint(r) >> 16);
}

// ---------------- in-LDS potrf of a 128x128 tile (rcp chain) -----------------
__device__ void potrf_factor(float (*Ls)[NB + 1]) {
  int tid = threadIdx.x;
  int lane = tid & 63, wid = tid >> 6;
  int tx = tid & 15, ty = tid >> 4;

  for (int pp = 0; pp < 8; ++pp) {
    int pc0 = pp * 16;
    if (wid == 0) {
      int ra = lane, rb = lane + 64;
      bool va = (ra >= pc0), vb = (rb >= pc0);
      float xa[16], xb[16];
#pragma unroll
      for (int c = 0; c < 16; ++c) {
        xa[c] = va ? Ls[ra][pc0 + c] : 0.0f;
        xb[c] = vb ? Ls[rb][pc0 + c] : 0.0f;
      }
#pragma unroll
      for (int j = 0; j < 16; ++j) {
        int jj = pc0 + j;
        float dv = (jj < 64) ? __shfl(xa[j], jj) : __shfl(xb[j], jj - 64);
        float di = __builtin_amdgcn_rcpf(dv);
        float ta = (ra > jj) ? xa[j] * di : 0.0f;
        float tb = (rb > jj) ? xb[j] * di : 0.0f;
#pragma unroll
        for (int c = j + 1; c < 16; ++c) {
          int rc = pc0 + c;
          float lc = (rc < 64) ? __shfl(xa[j], rc) : __shfl(xb[j], rc - 64);
          xa[c] -= ta * lc;
          xb[c] -= tb * lc;
        }
      }
#pragma unroll
      for (int c = 0; c < 16; ++c) {
        int rc = pc0 + c;
        float dc = (rc < 64) ? __shfl(xa[c], rc) : __shfl(xb[c], rc - 64);
        float sc = __builtin_amdgcn_rsqf(dc);
        xa[c] *= sc;
        xb[c] *= sc;
      }
      if (va) {
#pragma unroll
        for (int c = 0; c < 16; ++c) Ls[ra][pc0 + c] = xa[c];
      }
      if (vb) {
#pragma unroll
        for (int c = 0; c < 16; ++c) Ls[rb][pc0 + c] = xb[c];
      }
    }
    __syncthreads();

    int s0 = pc0 + 16;
    if (s0 < NB) {
      int r0 = ty * 8, c0 = tx * 8;
      if (r0 >= s0 && c0 >= s0) {
        float acc[8][8];
#pragma unroll
        for (int rr = 0; rr < 8; ++rr) {
          float4 m0 = *(const float4*)&Ls[r0 + rr][c0];
          float4 m1 = *(const float4*)&Ls[r0 + rr][c0 + 4];
          acc[rr][0] = m0.x; acc[rr][1] = m0.y; acc[rr][2] = m0.z; acc[rr][3] = m0.w;
          acc[rr][4] = m1.x; acc[rr][5] = m1.y; acc[rr][6] = m1.z; acc[rr][7] = m1.w;
        }
#pragma unroll
        for (int q = 0; q < 16; ++q) {
          float av[8], bv[8];
#pragma unroll
          for (int rr = 0; rr < 8; ++rr) av[rr] = Ls[r0 + rr][pc0 + q];
#pragma unroll
          for (int cc = 0; cc < 8; ++cc) bv[cc] = Ls[c0 + cc][pc0 + q];
#pragma unroll
          for (int rr = 0; rr < 8; ++rr)
#pragma unroll
            for (int cc = 0; cc < 8; ++cc) acc[rr][cc] -= av[rr] * bv[cc];
        }
#pragma unroll
        for (int rr = 0; rr < 8; ++rr) {
          *(float4*)&Ls[r0 + rr][c0] =
              make_float4(acc[rr][0], acc[rr][1], acc[rr][2], acc[rr][3]);
          *(float4*)&Ls[r0 + rr][c0 + 4] =
              make_float4(acc[rr][4], acc[rr][5], acc[rr][6], acc[rr][7]);
        }
      }
    }
    __syncthreads();
  }
}

__device__ void potrf_store(float* Msrc, float (*Ls)[NB + 1]) {
  int tid = threadIdx.x;
  for (int idx = tid; idx < NB * NB; idx += 256) {
    int i = idx >> 7, j = idx & (NB - 1);
    Msrc[(size_t)i * D + j] = (j <= i) ? Ls[i][j] : 0.0f;
  }
}

__global__ __launch_bounds__(256) void potrf_kernel(float* __restrict__ M, int kb)
{
  __shared__ float Ls[NB][NB + 1];
  int tid = threadIdx.x;
  float* Msrc = M + (size_t)kb * D + kb;
  for (int idx = tid; idx < NB * NB; idx += 256) {
    int i = idx >> 7, j = idx & (NB - 1);
    Ls[i][j] = Msrc[(size_t)i * D + j];
  }
  __syncthreads();
  potrf_factor(Ls);
  potrf_store(Msrc, Ls);
}

// ---------------- A -> split-bf16 shadow (hi/lo) ------------------------------
__global__ __launch_bounds__(256) void convA_kernel(
    const float* __restrict__ A, ush* __restrict__ AhG, ush* __restrict__ AlG)
{
  size_t idx = ((size_t)blockIdx.x * 256 + threadIdx.x) * 8;
  float4 v0 = *(const float4*)(A + idx);
  float4 v1 = *(const float4*)(A + idx + 4);
  HL p0 = split2(v0.x, v0.y), p1 = split2(v0.z, v0.w);
  HL p2 = split2(v1.x, v1.y), p3 = split2(v1.z, v1.w);
  uint4v h = {p0.h, p1.h, p2.h, p3.h};
  uint4v l = {p0.l, p1.l, p2.l, p3.l};
  *(uint4v*)(AhG + idx) = h;
  *(uint4v*)(AlG + idx) = l;
}

// ---------------- syrk0: M = A·A^T + diag(softplus(n)), lower tiles ----------
// SHA: stage from pre-split bf16 shadow of A (no split VALU in the K-loop).
template <bool SHA>
__global__ __launch_bounds__(256) void syrk0_kernel(
    const float* __restrict__ Asrc, const float* __restrict__ nvec,
    float* __restrict__ Mout,
    const ush* __restrict__ AhG, const ush* __restrict__ AlG)
{
  __shared__ ush Ah[NB][LDP], Al[NB][LDP];
  __shared__ ush Bh[NB][LDP], Bl[NB][LDP];

  int b = blockIdx.x;
  int ti = (int)((sqrtf(8.0f * (float)b + 1.0f) - 1.0f) * 0.5f);
  while ((ti + 1) * (ti + 2) / 2 <= b) ++ti;
  while (ti * (ti + 1) / 2 > b) --ti;
  int tj = b - ti * (ti + 1) / 2;
  int row0 = ti * NB, col0 = tj * NB;

  int tid = threadIdx.x;
  int lane = tid & 63, wid = tid >> 6;
  int wr = wid >> 1, wc = wid & 1;
  int srow = tid >> 1;
  int scg = (tid & 1) * 16;

  f32x4 acc[4][4];
#pragma unroll
  for (int m = 0; m < 4; ++m)
#pragma unroll
    for (int n = 0; n < 4; ++n) acc[m][n] = (f32x4){0.f, 0.f, 0.f, 0.f};

  int lr16 = lane & 15, kof = (lane >> 4) * 8;

  for (int kk = 0; kk < D; kk += KC) {
    if (SHA) {
      const ush* pah = AhG + (size_t)(row0 + srow) * D + kk + scg;
      const ush* pal = AlG + (size_t)(row0 + srow) * D + kk + scg;
      const ush* pbh = AhG + (size_t)(col0 + srow) * D + kk + scg;
      const ush* pbl = AlG + (size_t)(col0 + srow) * D + kk + scg;
      short8 ah0 = *(const short8*)pah, ah1 = *(const short8*)(pah + 8);
      short8 al0 = *(const short8*)pal, al1 = *(const short8*)(pal + 8);
      short8 bh0 = *(const short8*)pbh, bh1 = *(const short8*)(pbh + 8);
      short8 bl0 = *(const short8*)pbl, bl1 = *(const short8*)(pbl + 8);
      __syncthreads();
      *(short8*)&Ah[srow][scg] = ah0;  *(short8*)&Ah[srow][scg + 8] = ah1;
      *(short8*)&Al[srow][scg] = al0;  *(short8*)&Al[srow][scg + 8] = al1;
      *(short8*)&Bh[srow][scg] = bh0;  *(short8*)&Bh[srow][scg + 8] = bh1;
      *(short8*)&Bl[srow][scg] = bl0;  *(short8*)&Bl[srow][scg + 8] = bl1;
    } else {
      const float* pa = Asrc + (size_t)(row0 + srow) * D + kk + scg;
      const float* pb = Asrc + (size_t)(col0 + srow) * D + kk + scg;
      float4 av0 = *(const float4*)(pa + 0), av1 = *(const float4*)(pa + 4);
      float4 av2 = *(const float4*)(pa + 8), av3 = *(const float4*)(pa + 12);
      float4 bv0 = *(const float4*)(pb + 0), bv1 = *(const float4*)(pb + 4);
      float4 bv2 = *(const float4*)(pb + 8), bv3 = *(const float4*)(pb + 12);
      __syncthreads();
      {
        HL p0 = split2(av0.x, av0.y), p1 = split2(av0.z, av0.w);
        HL p2 = split2(av1.x, av1.y), p3 = split2(av1.z, av1.w);
        HL p4 = split2(av2.x, av2.y), p5 = split2(av2.z, av2.w);
        HL p6 = split2(av3.x, av3.y), p7 = split2(av3.z, av3.w);
        uint4v h0 = {p0.h, p1.h, p2.h, p3.h}, l0 = {p0.l, p1.l, p2.l, p3.l};
        uint4v h1 = {p4.h, p5.h, p6.h, p7.h}, l1 = {p4.l, p5.l, p6.l, p7.l};
        *(uint4v*)&Ah[srow][scg] = h0;  *(uint4v*)&Ah[srow][scg + 8] = h1;
        *(uint4v*)&Al[srow][scg] = l0;  *(uint4v*)&Al[srow][scg + 8] = l1;
      }
      {
        HL p0 = split2(bv0.x, bv0.y), p1 = split2(bv0.z, bv0.w);
        HL p2 = split2(bv1.x, bv1.y), p3 = split2(bv1.z, bv1.w);
        HL p4 = split2(bv2.x, bv2.y), p5 = split2(bv2.z, bv2.w);
        HL p6 = split2(bv3.x, bv3.y), p7 = split2(bv3.z, bv3.w);
        uint4v h0 = {p0.h, p1.h, p2.h, p3.h}, l0 = {p0.l, p1.l, p2.l, p3.l};
        uint4v h1 = {p4.h, p5.h, p6.h, p7.h}, l1 = {p4.l, p5.l, p6.l, p7.l};
        *(uint4v*)&Bh[srow][scg] = h0;  *(uint4v*)&Bh[srow][scg + 8] = h1;
        *(uint4v*)&Bl[srow][scg] = l0;  *(uint4v*)&Bl[srow][scg + 8] = l1;
      }
    }
    __syncthreads();

    short8 ah[4], al[4], bh[4], bl[4];
#pragma unroll
    for (int m = 0; m < 4; ++m) {
      int r = wr * 64 + m * 16 + lr16;
      ah[m] = *(const short8*)&Ah[r][kof];
      al[m] = *(const short8*)&Al[r][kof];
    }
#pragma unroll
    for (int n = 0; n < 4; ++n) {
      int c = wc * 64 + n * 16 + lr16;
      bh[n] = *(const short8*)&Bh[c][kof];
      bl[n] = *(const short8*)&Bl[c][kof];
    }
#pragma unroll
    for (int m = 0; m < 4; ++m)
#pragma unroll
      for (int n = 0; n < 4; ++n) {
        acc[m][n] = __builtin_amdgcn_mfma_f32_16x16x32_bf16(ah[m], bh[n], acc[m][n], 0, 0, 0);
        acc[m][n] = __builtin_amdgcn_mfma_f32_16x16x32_bf16(ah[m], bl[n], acc[m][n], 0, 0, 0);
        acc[m][n] = __builtin_amdgcn_mfma_f32_16x16x32_bf16(al[m], bh[n], acc[m][n], 0, 0, 0);
      }
  }

  int cl = lane & 15, rg = (lane >> 4) * 4;
#pragma unroll
  for (int m = 0; m < 4; ++m) {
#pragma unroll
    for (int n = 0; n < 4; ++n) {
      int gi0 = row0 + wr * 64 + m * 16 + rg;
      int gj = col0 + wc * 64 + n * 16 + cl;
#pragma unroll
      for (int r = 0; r < 4; ++r) {
        int gi = gi0 + r;
        float v = acc[m][n][r];
        if (gi == gj) v += softplusf(nvec[gi]);
        Mout[(size_t)gi * D + gj] = v;
      }
    }
  }

  if (ti > tj) {   // mirror-zero the upper tile
    float4 z = make_float4(0.f, 0.f, 0.f, 0.f);
    int zr = tid >> 1;
    int zc0 = (tid & 1) * 64;
    float* zp = Mout + (size_t)(col0 + zr) * D + row0 + zc0;
#pragma unroll
    for (int q = 0; q < 16; ++q) *(float4*)(zp + 4 * q) = z;
  }
}

// ---------------- trsm: 8 rows/block (R7 geometry), optional shadow write ----
template <bool SH>
__global__ __launch_bounds__(256) void trsm_kernel(
    float* __restrict__ M, int kb, ush* __restrict__ shH, ush* __restrict__ shL)
{
  __shared__ float Ls[NB][NB + 1];
  __shared__ float dinv[NB];
  int tid = threadIdx.x;
  const float* Lsrc = M + (size_t)kb * D + kb;
  for (int idx = tid; idx < NB * NB; idx += 256) {
    int i = idx >> 7, j = idx & (NB - 1);
    Ls[i][j] = Lsrc[(size_t)i * D + j];   // upper zeroed by potrf_store
  }
  __syncthreads();
  if (tid < NB) dinv[tid] = 1.0f / Ls[tid][tid];
  __syncthreads();
  int lane = tid & 63, w = tid >> 6;
  size_t r0 = (size_t)(kb + NB) + (size_t)blockIdx.x * 8 + w * 2;
  float* p0 = M + r0 * D + kb;
  float* p1 = p0 + D;
  float x0l = p0[lane], x0h = p0[64 + lane];
  float x1l = p1[lane], x1h = p1[64 + lane];
  for (int p = 0; p < 64; ++p) {
    float dv = dinv[p];
    float xp0 = __shfl(x0l, p) * dv;
    float xp1 = __shfl(x1l, p) * dv;
    float Llo = Ls[lane][p];
    float Lhi = Ls[64 + lane][p];
    if (lane == p)      { x0l = xp0; x1l = xp1; }
    else if (lane > p)  { x0l -= xp0 * Llo; x1l -= xp1 * Llo; }
    x0h -= xp0 * Lhi;
    x1h -= xp1 * Lhi;
  }
  for (int p = 64; p < NB; ++p) {
    int q = p - 64;
    float dv = dinv[p];
    float xp0 = __shfl(x0h, q) * dv;
    float xp1 = __shfl(x1h, q) * dv;
    float Lhi = Ls[64 + lane][p];
    if (lane == q)      { x0h = xp0; x1h = xp1; }
    else if (lane > q)  { x0h -= xp0 * Lhi; x1h -= xp1 * Lhi; }
  }
  p0[lane] = x0l; p0[64 + lane] = x0h;
  p1[lane] = x1l; p1[64 + lane] = x1h;
  if (SH) {
    ush h, l;
    split1(x0l, h, l);
    shH[r0 * NB + lane] = h;        shL[r0 * NB + lane] = l;
    split1(x0h, h, l);
    shH[r0 * NB + 64 + lane] = h;   shL[r0 * NB + 64 + lane] = l;
    split1(x1l, h, l);
    shH[(r0 + 1) * NB + lane] = h;      shL[(r0 + 1) * NB + lane] = l;
    split1(x1h, h, l);
    shH[(r0 + 1) * NB + 64 + lane] = h; shL[(r0 + 1) * NB + 64 + lane] = l;
  }
}

// ---------------- K=128 GEMM from fp32 rows (fallback) -----------------------
__device__ void gemm_bt(const float* __restrict__ Ap, const float* __restrict__ Bp,
                        f32x4 (&acc)[4][4],
                        ush (*Ah)[LDP], ush (*Al)[LDP],
                        ush (*Bh)[LDP], ush (*Bl)[LDP])
{
  int tid = threadIdx.x;
  int lane = tid & 63, wid = tid >> 6;
  int wr = wid >> 1, wc = wid & 1;
  int srow = tid >> 1, scg = (tid & 1) * 16;
  int lr16 = lane & 15, kof = (lane >> 4) * 8;

  for (int kk = 0; kk < NB; kk += KC) {
    const float* pa = Ap + (size_t)srow * D + kk + scg;
    const float* pb = Bp + (size_t)srow * D + kk + scg;
    float4 av0 = *(const float4*)(pa + 0), av1 = *(const float4*)(pa + 4);
    float4 av2 = *(const float4*)(pa + 8), av3 = *(const float4*)(pa + 12);
    float4 bv0 = *(const float4*)(pb + 0), bv1 = *(const float4*)(pb + 4);
    float4 bv2 = *(const float4*)(pb + 8), bv3 = *(const float4*)(pb + 12);

    __syncthreads();
    {
      HL p0 = split2(av0.x, av0.y), p1 = split2(av0.z, av0.w);
      HL p2 = split2(av1.x, av1.y), p3 = split2(av1.z, av1.w);
      HL p4 = split2(av2.x, av2.y), p5 = split2(av2.z, av2.w);
      HL p6 = split2(av3.x, av3.y), p7 = split2(av3.z, av3.w);
      uint4v h0 = {p0.h, p1.h, p2.h, p3.h}, l0 = {p0.l, p1.l, p2.l, p3.l};
      uint4v h1 = {p4.h, p5.h, p6.h, p7.h}, l1 = {p4.l, p5.l, p6.l, p7.l};
      *(uint4v*)&Ah[srow][scg] = h0;  *(uint4v*)&Ah[srow][scg + 8] = h1;
      *(uint4v*)&Al[srow][scg] = l0;  *(uint4v*)&Al[srow][scg + 8] = l1;
    }
    {
      HL p0 = split2(bv0.x, bv0.y), p1 = split2(bv0.z, bv0.w);
      HL p2 = split2(bv1.x, bv1.y), p3 = split2(bv1.z, bv1.w);
      HL p4 = split2(bv2.x, bv2.y), p5 = split2(bv2.z, bv2.w);
      HL p6 = split2(bv3.x, bv3.y), p7 = split2(bv3.z, bv3.w);
      uint4v h0 = {p0.h, p1.h, p2.h, p3.h}, l0 = {p0.l, p1.l, p2.l, p3.l};
      uint4v h1 = {p4.h, p5.h, p6.h, p7.h}, l1 = {p4.l, p5.l, p6.l, p7.l};
      *(uint4v*)&Bh[srow][scg] = h0;  *(uint4v*)&Bh[srow][scg + 8] = h1;
      *(uint4v*)&Bl[srow][scg] = l0;  *(uint4v*)&Bl[srow][scg + 8] = l1;
    }
    __syncthreads();

    short8 ah[4], al[4], bh[4], bl[4];
#pragma unroll
    for (int m = 0; m < 4; ++m) {
      int r = wr * 64 + m * 16 + lr16;
      ah[m] = *(const short8*)&Ah[r][kof];
      al[m] = *(const short8*)&Al[r][kof];
    }
#pragma unroll
    for (int n = 0; n < 4; ++n) {
      int c = wc * 64 + n * 16 + lr16;
      bh[n] = *(const short8*)&Bh[c][kof];
      bl[n] = *(const short8*)&Bl[c][kof];
    }
#pragma unroll
    for (int m = 0; m < 4; ++m)
#pragma unroll
      for (int n = 0; n < 4; ++n) {
        acc[m][n] = __builtin_amdgcn_mfma_f32_16x16x32_bf16(ah[m], bh[n], acc[m][n], 0, 0, 0);
        acc[m][n] = __builtin_amdgcn_mfma_f32_16x16x32_bf16(ah[m], bl[n], acc[m][n], 0, 0, 0);
        acc[m][n] = __builtin_amdgcn_mfma_f32_16x16x32_bf16(al[m], bh[n], acc[m][n], 0, 0, 0);
      }
  }
}

// ---------------- K=128 GEMM from bf16 shadow rows ---------------------------
__device__ void gemm_bt_sh(const ush* __restrict__ AhG, const ush* __restrict__ AlG,
                           const ush* __restrict__ BhG, const ush* __restrict__ BlG,
                           f32x4 (&acc)[4][4],
                           ush (*Ah)[LDP], ush (*Al)[LDP],
                           ush (*Bh)[LDP], ush (*Bl)[LDP])
{
  int tid = threadIdx.x;
  int lane = tid & 63, wid = tid >> 6;
  int wr = wid >> 1, wc = wid & 1;
  int srow = tid >> 1, scg = (tid & 1) * 16;
  int lr16 = lane & 15, kof = (lane >> 4) * 8;

  for (int kk = 0; kk < NB; kk += KC) {
    const ush* pah = AhG + (size_t)srow * NB + kk + scg;
    const ush* pal = AlG + (size_t)srow * NB + kk + scg;
    const ush* pbh = BhG + (size_t)srow * NB + kk + scg;
    const ush* pbl = BlG + (size_t)srow * NB + kk + scg;
    short8 vah0 = *(const short8*)(pah), vah1 = *(const short8*)(pah + 8);
    short8 val0 = *(const short8*)(pal), val1 = *(const short8*)(pal + 8);
    short8 vbh0 = *(const short8*)(pbh), vbh1 = *(const short8*)(pbh + 8);
    short8 vbl0 = *(const short8*)(pbl), vbl1 = *(const short8*)(pbl + 8);

    __syncthreads();
    *(short8*)&Ah[srow][scg] = vah0;  *(short8*)&Ah[srow][scg + 8] = vah1;
    *(short8*)&Al[srow][scg] = val0;  *(short8*)&Al[srow][scg + 8] = val1;
    *(short8*)&Bh[srow][scg] = vbh0;  *(short8*)&Bh[srow][scg + 8] = vbh1;
    *(short8*)&Bl[srow][scg] = vbl0;  *(short8*)&Bl[srow][scg + 8] = vbl1;
    __syncthreads();

    short8 ah[4], al[4], bh[4], bl[4];
#pragma unroll
    for (int m = 0; m < 4; ++m) {
      int r = wr * 64 + m * 16 + lr16;
      ah[m] = *(const short8*)&Ah[r][kof];
      al[m] = *(const short8*)&Al[r][kof];
    }
#pragma unroll
    for (int n = 0; n < 4; ++n) {
      int c = wc * 64 + n * 16 + lr16;
      bh[n] = *(const short8*)&Bh[c][kof];
      bl[n] = *(const short8*)&Bl[c][kof];
    }
#pragma unroll
    for (int m = 0; m < 4; ++m)
#pragma unroll
      for (int n = 0; n < 4; ++n) {
        acc[m][n] = __builtin_amdgcn_mfma_f32_16x16x32_bf16(ah[m], bh[n], acc[m][n], 0, 0, 0);
        acc[m][n] = __builtin_amdgcn_mfma_f32_16x16x32_bf16(ah[m], bl[n], acc[m][n], 0, 0, 0);
        acc[m][n] = __builtin_amdgcn_mfma_f32_16x16x32_bf16(al[m], bh[n], acc[m][n], 0, 0, 0);
      }
  }
}

// ---------------- trailing update; block 0 fuses potrf of next diag ----------
template <bool SH>
__global__ __launch_bounds__(256) void syrk1_kernel(
    float* __restrict__ M, int kb,
    const ush* __restrict__ shH, const ush* __restrict__ shL)
{
  __shared__ __align__(16) unsigned char smem[66560];
  ush (*Ah)[LDP] = (ush(*)[LDP])(smem);
  ush (*Al)[LDP] = (ush(*)[LDP])(smem + 10240);
  ush (*Bh)[LDP] = (ush(*)[LDP])(smem + 20480);
  ush (*Bl)[LDP] = (ush(*)[LDP])(smem + 30720);
  float (*Ls)[NB + 1] = (float(*)[NB + 1])smem;

  float* Mout = M + (size_t)(kb + NB) * D + (kb + NB);
  const float* Xsrc = M + (size_t)(kb + NB) * D + kb;

  int s = blockIdx.x;
  int ti = (int)((sqrtf(8.0f * (float)s + 1.0f) - 1.0f) * 0.5f);
  while ((ti + 1) * (ti + 2) / 2 <= s) ++ti;
  while (ti * (ti + 1) / 2 > s) --ti;
  int tj = s - ti * (ti + 1) / 2;
  int row0 = ti * NB, col0 = tj * NB;

  int tid = threadIdx.x;
  int lane = tid & 63, wid = tid >> 6;
  int wr = wid >> 1, wc = wid & 1;
  int cl = lane & 15, rg = (lane >> 4) * 4;

  f32x4 acc[4][4];
#pragma unroll
  for (int m = 0; m < 4; ++m)
#pragma unroll
    for (int n = 0; n < 4; ++n) acc[m][n] = (f32x4){0.f, 0.f, 0.f, 0.f};

  if (SH) {
    size_t ra = (size_t)(kb + NB + row0) * NB;
    size_t rb = (size_t)(kb + NB + col0) * NB;
    gemm_bt_sh(shH + ra, shL + ra, shH + rb, shL + rb, acc, Ah, Al, Bh, Bl);
  } else {
    gemm_bt(Xsrc + (size_t)row0 * D, Xsrc + (size_t)col0 * D, acc, Ah, Al, Bh, Bl);
  }

  if (s == 0) {
    __syncthreads();   // staging LDS reads done before smem reuse as Ls
#pragma unroll
    for (int m = 0; m < 4; ++m)
#pragma unroll
      for (int n = 0; n < 4; ++n) {
        int li0 = wr * 64 + m * 16 + rg;
        int lj = wc * 64 + n * 16 + cl;
#pragma unroll
        for (int r = 0; r < 4; ++r) {
          int li = li0 + r;
          Ls[li][lj] = Mout[(size_t)li * D + lj] - acc[m][n][r];
        }
      }
    __syncthreads();
    potrf_factor(Ls);
    potrf_store(Mout, Ls);
    return;
  }

#pragma unroll
  for (int m = 0; m < 4; ++m) {
#pragma unroll
    for (int n = 0; n < 4; ++n) {
      int gi0 = row0 + wr * 64 + m * 16 + rg;
      int gj = col0 + wc * 64 + n * 16 + cl;
#pragma unroll
      for (int r = 0; r < 4; ++r) {
        int gi = gi0 + r;
        Mout[(size_t)gi * D + gj] -= acc[m][n][r];
      }
    }
  }
}

extern "C" void kernel_launch(void* const* d_in, const int* in_sizes, int n_in,
                              void* d_out, int out_size, void* d_ws, size_t ws_size,
                              hipStream_t stream)
{
  (void)in_sizes; (void)n_in; (void)out_size;
  const float* A  = (const float*)d_in[0];
  const float* nv = (const float*)d_in[1];
  float* M = (float*)d_out;

  // ws layout: [X-shadow hi 1MB][X-shadow lo 1MB][A-shadow hi 32MB][A-shadow lo 32MB]
  const size_t xsh_elems = (size_t)D * NB;
  const size_t ash_elems = (size_t)D * D;
  const size_t need_x = 2 * xsh_elems * sizeof(ush);                 // 2 MB
  const size_t need_a = need_x + 2 * ash_elems * sizeof(ush);        // +64 MB
  bool shX = (ws_size >= need_x);
  bool shA = (ws_size >= need_a);
  ush* xH = (ush*)d_ws;
  ush* xL = xH + xsh_elems;
  ush* aH = xL + xsh_elems;
  ush* aL = aH + ash_elems;

  if (shA) {
    convA_kernel<<<(int)(ash_elems / 8 / 256), 256, 0, stream>>>(A, aH, aL);
    syrk0_kernel<true><<<NT * (NT + 1) / 2, 256, 0, stream>>>(A, nv, M, aH, aL);
  } else {
    syrk0_kernel<false><<<NT * (NT + 1) / 2, 256, 0, stream>>>(A, nv, M, nullptr, nullptr);
  }
  potrf_kernel<<<1, 256, 0, stream>>>(M, 0);

  for (int k = 0; k <= 30; ++k) {
    int kb = k * NB;
    int T = D - kb - NB;
    int t = T / NB;
    if (shX) {
      trsm_kernel<true><<<T / 8, 256, 0, stream>>>(M, kb, xH, xL);
      syrk1_kernel<true><<<t * (t + 1) / 2, 256, 0, stream>>>(M, kb, xH, xL);
    } else {
      trsm_kernel<false><<<T / 8, 256, 0, stream>>>(M, kb, nullptr, nullptr);
      syrk1_kernel<false><<<t * (t + 1) / 2, 256, 0, stream>>>(M, kb, nullptr, nullptr);
    }
  }
}